// Round 13
// baseline (474.018 us; speedup 1.0000x reference)
//
#include <hip/hip_runtime.h>
#include <cstddef>
#include <cstdint>

static constexpr int Bb  = 4;
static constexpr int Ll  = 4096;
static constexpr int Mm  = 16384;     // B*L
static constexpr int KK  = 1024;      // GEMM K
static constexpr int NCH = 128;       // scan chunks
static constexpr int CHL = 32;        // rows per chunk

typedef __attribute__((ext_vector_type(8)))  short short8;   // 8 x bf16
typedef __attribute__((ext_vector_type(4)))  float f32x4;
typedef __attribute__((ext_vector_type(16))) float f32x16;

#define AS1C(p) ((const __attribute__((address_space(1))) void*)(p))
#define AS3(p)  ((__attribute__((address_space(3))) void*)(p))

// ---------------- scalar helpers ----------------
__device__ __forceinline__ float b2f(unsigned short u) {
    union { unsigned int i; float f; } c; c.i = ((unsigned int)u) << 16; return c.f;
}
__device__ __forceinline__ unsigned short f2b(float f) {
    union { float f; unsigned int i; } c; c.f = f;
    unsigned int r = c.i + 0x7fffu + ((c.i >> 16) & 1u);
    return (unsigned short)(r >> 16);
}
__device__ __forceinline__ float4 bq2f(ushort4 u) {
    return make_float4(b2f(u.x), b2f(u.y), b2f(u.z), b2f(u.w));
}
__device__ __forceinline__ ushort4 f2bq(float4 v) {
    ushort4 o; o.x = f2b(v.x); o.y = f2b(v.y); o.z = f2b(v.z); o.w = f2b(v.w); return o;
}
__device__ __forceinline__ float4 qmul(const float4 a, const float4 b) {
    float4 r;
    r.x = a.x * b.x - a.y * b.y - a.z * b.z - a.w * b.w;
    r.y = a.x * b.y + a.y * b.x + a.z * b.w - a.w * b.z;
    r.z = a.x * b.z - a.y * b.w + a.z * b.x + a.w * b.y;
    r.w = a.x * b.w + a.y * b.z - a.z * b.y + a.w * b.x;
    return r;
}
__device__ __forceinline__ float4 qconj(const float4 a) {
    return make_float4(a.x, -a.y, -a.z, -a.w);
}
__device__ __forceinline__ float4 qnorm(const float4 a) {
    float n = sqrtf(a.x * a.x + a.y * a.y + a.z * a.z + a.w * a.w);
    float inv = 1.0f / fmaxf(n, 1e-12f);
    return make_float4(a.x * inv, a.y * inv, a.z * inv, a.w * inv);
}
// A&S 7.1.26 erf (|eps| <= 1.5e-7), branchless
__device__ __forceinline__ float gelu_fast(float v) {
    const float a = fabsf(v) * 0.70710678118654752f;
    const float t = 1.0f / (1.0f + 0.3275911f * a);
    const float p = t * (0.254829592f + t * (-0.284496736f + t * (1.421413741f
                   + t * (-1.453152027f + t * 1.061405429f))));
    const float e = __expf(-a * a);
    const float erfa = 1.0f - p * e;
    return 0.5f * v * (1.0f + copysignf(erfa, v));
}

// ---------------- fp32 -> bf16 convert ----------------
__global__ __launch_bounds__(256)
void conv_k(const float* __restrict__ src, unsigned short* __restrict__ dst, int n4)
{
    const int i = blockIdx.x * 256 + threadIdx.x;
    if (i >= n4) return;
    const float4 v = reinterpret_cast<const float4*>(src)[i];
    reinterpret_cast<ushort4*>(dst)[i] = f2bq(v);
}

// ---------------- W[K,N] fp32 -> W^T[N,K] bf16 ----------------
__global__ __launch_bounds__(256)
void wtrans_k(const float* __restrict__ src, unsigned short* __restrict__ dst)
{
    __shared__ float t[32][33];
    const int tx = threadIdx.x, ty = threadIdx.y;       // 32 x 8
    const int n0 = blockIdx.x * 32, k0 = blockIdx.y * 32;
    #pragma unroll
    for (int j = ty; j < 32; j += 8)
        t[j][tx] = src[(size_t)(k0 + j) * 1024 + n0 + tx];
    __syncthreads();
    #pragma unroll
    for (int j = ty; j < 32; j += 8)
        dst[(size_t)(n0 + j) * 1024 + k0 + tx] = f2b(t[tx][j]);
}

// ---------------- bias concat ----------------
__global__ __launch_bounds__(256)
void bcat_k(const float* __restrict__ bk1, const float* __restrict__ bq1,
            const float* __restrict__ bv,  const float* __restrict__ bk2,
            const float* __restrict__ bq2, float* __restrict__ b1,
            float* __restrict__ b2)
{
    const int i = blockIdx.x * 256 + threadIdx.x;
    if (i < 3072) b1[i] = (i < 1024) ? bk1[i] : (i < 2048 ? bq1[i - 1024] : bv[i - 2048]);
    if (i < 2048) b2[i] = (i < 1024) ? bk2[i] : bq2[i - 1024];
}

// ---- 128x128 MFMA GEMM, 32x32x16 frags, BK=32, 3-buf depth-2, 1 barrier/iter ----
// LDS 48KB static: buf c @ c*16384 {A 8KB, B 8KB @ +8192}; 3 blocks/CU.
// Unit = [128 rows][16 k] bf16, 4KB/k-step (2 k-steps per K-32 tile).
// Line = 4 rows x 128B; slot s = (((r&3)<<1)|chunk) ^ ((r>>2)&7) -> balanced (8 lanes/slot).
// Iter t: {8 ds_read_b128 buf t%3, STAGE buf(t+2)%3, 8 MFMA 32x32x16,
//          vmcnt(4) counted, barrier}.
// MODE 0: A=xb, BT=wcat1[3072,1024]; n0<2048: gelu->bf16 outH ; else ->bf16 outV
// MODE 1: A=h[M,2048] block-diag (aoff=1024 for n0>=1024) -> bf16 outH (qb2)
// MODE 2: A=ln, BT=woT -> f32 outF = acc+bias+resid
template<int MODE>
__global__ __launch_bounds__(256, 3)
void gemm128_k(const unsigned short* __restrict__ A, int astride,
               const unsigned short* __restrict__ BT,
               const float* __restrict__ bias,
               const float* __restrict__ resid,
               unsigned short* __restrict__ outH,
               unsigned short* __restrict__ outV,
               float* __restrict__ outF,
               int Nn)
{
    __shared__ char smem[49152];
    const int tid  = threadIdx.x;
    const int lane = tid & 63;
    const int w    = tid >> 6;       // 0..3
    const int wr   = w >> 1;         // 0..1 -> 64-row half
    const int wc   = w & 1;          // 0..1 -> 64-col half

    // XCD-aware bijective swizzle (gridDim.x % 8 == 0)
    const int nwg = gridDim.x;
    const int cpx = nwg >> 3;
    const int bid = blockIdx.x;
    const int swz = (bid & 7) * cpx + (bid >> 3);
    const int nTN = Nn >> 7;
    const int m0  = (swz / nTN) << 7;
    const int n0  = (swz % nTN) << 7;
    const int aoff = (MODE == 1 && n0 >= 1024) ? 1024 : 0;

    // staging source: linear slot s_lin = c2*256+tid over 8KB (2 units x 32 lines).
    // line = s_lin>>3 ; unit = line>>5 ; lu = line&31 ; v = (s_lin&7)^(lu&7)
    // row r = lu*4 + (v>>1) ; k elem = unit*16 + (v&1)*8
    const unsigned short* gA[2];
    const unsigned short* gB[2];
    #pragma unroll
    for (int c2 = 0; c2 < 2; ++c2) {
        const int s_lin = c2 * 256 + tid;
        const int line  = s_lin >> 3;
        const int lu    = line & 31;
        const int unit  = line >> 5;
        const int v     = (s_lin & 7) ^ (lu & 7);
        const int r     = lu * 4 + (v >> 1);
        const int ke    = unit * 16 + (v & 1) * 8;
        gA[c2] = A + (size_t)(m0 + r) * astride + aoff + ke;
        gB[c2] = BT + (size_t)(n0 + r) * KK + ke;
    }

    auto STAGE = [&](int c, int koff) {
        #pragma unroll
        for (int c2 = 0; c2 < 2; ++c2)
            __builtin_amdgcn_global_load_lds(AS1C(gA[c2] + koff),
                AS3(smem + c * 16384 + c2 * 4096 + w * 1024), 16, 0, 0);
        #pragma unroll
        for (int c2 = 0; c2 < 2; ++c2)
            __builtin_amdgcn_global_load_lds(AS1C(gB[c2] + koff),
                AS3(smem + c * 16384 + 8192 + c2 * 4096 + w * 1024), 16, 0, 0);
    };

    // fragment read offsets: frag (mi/ni, kstep): row r = half*64 + mi*32 + (lane&31),
    // chunk = lane>>5 ; off = kstep*4096 + (r>>2)*128 + (((((r&3)<<1)|chunk)^((r>>2)&7))<<4)
    const int l31 = lane & 31;
    const int chk = lane >> 5;
    int offA[2][2], offB[2][2];   // [kstep][mi/ni]
    #pragma unroll
    for (int ks = 0; ks < 2; ++ks) {
        #pragma unroll
        for (int mi = 0; mi < 2; ++mi) {
            const int r = wr * 64 + mi * 32 + l31;
            offA[ks][mi] = ks * 4096 + (r >> 2) * 128 + (((((r & 3) << 1) | chk) ^ ((r >> 2) & 7)) << 4);
        }
        #pragma unroll
        for (int ni = 0; ni < 2; ++ni) {
            const int r = wc * 64 + ni * 32 + l31;
            offB[ks][ni] = 8192 + ks * 4096 + (r >> 2) * 128 + (((((r & 3) << 1) | chk) ^ ((r >> 2) & 7)) << 4);
        }
    }

    f32x16 acc[2][2] = {};

    // iteration: read buf rb (8 ds_read first), stage tile t+2 into sb, 8 MFMA.
    auto ITER = [&](int rb, int sb, int ks2, int vm) {
        const int cb = rb * 16384;
        short8 af[2][2], bf[2][2];
        #pragma unroll
        for (int ks = 0; ks < 2; ++ks) {
            #pragma unroll
            for (int mi = 0; mi < 2; ++mi) af[ks][mi] = *(const short8*)(smem + cb + offA[ks][mi]);
            #pragma unroll
            for (int ni = 0; ni < 2; ++ni) bf[ks][ni] = *(const short8*)(smem + cb + offB[ks][ni]);
        }
        if (ks2 >= 0) STAGE(sb, ks2);
        #pragma unroll
        for (int ks = 0; ks < 2; ++ks)
            #pragma unroll
            for (int mi = 0; mi < 2; ++mi)
                #pragma unroll
                for (int ni = 0; ni < 2; ++ni)
                    acc[mi][ni] = __builtin_amdgcn_mfma_f32_32x32x16_bf16(
                        af[ks][mi], bf[ks][ni], acc[mi][ni], 0, 0, 0);
        if (vm == 4)      asm volatile("s_waitcnt vmcnt(4)" ::: "memory");
        else if (vm == 0) asm volatile("s_waitcnt vmcnt(0)" ::: "memory");
        if (vm >= 0) __builtin_amdgcn_s_barrier();
    };

    // prologue: stage tiles 0,1 into bufs 0,1 ; drain tile0 (oldest 4), publish
    STAGE(0, 0);
    STAGE(1, 32);
    asm volatile("s_waitcnt vmcnt(4)" ::: "memory");
    __builtin_amdgcn_s_barrier();

    // steady state: t = 0..29 (stage t+2), unrolled x3 for static buf indices
    #pragma unroll 1
    for (int t0 = 0; t0 < 30; t0 += 3) {
        ITER(0, 2, (t0 + 2) * 32, 4);
        ITER(1, 0, (t0 + 3) * 32, 4);
        ITER(2, 1, (t0 + 4) * 32, 4);
    }
    ITER(0, 0, -1, 0);    // t=30: read buf0, drain tile31
    ITER(1, 0, -1, -1);   // t=31: read buf1, no wait
    __syncthreads();      // retire LDS reads before epilogue reuses smem

    // ---- epilogue: 32x32 C layout col = lane&31, row = (reg&3)+8*(reg>>2)+4*(lane>>5) ----
    const int colb = n0 + wc * 64 + l31;
    float bv[2];
    #pragma unroll
    for (int ni = 0; ni < 2; ++ni) bv[ni] = bias[colb + ni * 32];

    if (MODE == 2) {
        #pragma unroll
        for (int ni = 0; ni < 2; ++ni) {
            const int col = colb + ni * 32;
            #pragma unroll
            for (int mi = 0; mi < 2; ++mi) {
                #pragma unroll
                for (int rg = 0; rg < 16; ++rg) {
                    const int row = m0 + wr * 64 + mi * 32 + (rg & 3) + 8 * (rg >> 2) + 4 * chk;
                    const size_t ix = (size_t)row * 1024 + col;
                    outF[ix] = acc[mi][ni][rg] + bv[ni] + resid[ix];
                }
            }
        }
    } else {
        const bool dogelu = (MODE == 0) && (n0 < 2048);
        unsigned short* dst;
        int stride, col0;
        if (MODE == 0 && n0 >= 2048) { dst = outV; stride = 1024; col0 = n0 - 2048; }
        else                         { dst = outH; stride = 2048; col0 = n0; }
        // stage 64 rows at a time through LDS for coalesced 16B stores
        unsigned short* eb = (unsigned short*)smem;   // [64][136] = 17.4 KB
        #pragma unroll
        for (int pass = 0; pass < 2; ++pass) {
            if (wr == pass) {
                #pragma unroll
                for (int ni = 0; ni < 2; ++ni) {
                    const int col = wc * 64 + ni * 32 + l31;
                    #pragma unroll
                    for (int mi = 0; mi < 2; ++mi) {
                        #pragma unroll
                        for (int rg = 0; rg < 16; ++rg) {
                            float v = acc[mi][ni][rg] + bv[ni];
                            if (dogelu) v = gelu_fast(v);
                            const int er2 = mi * 32 + (rg & 3) + 8 * (rg >> 2) + 4 * chk;
                            eb[er2 * 136 + col] = f2b(v);
                        }
                    }
                }
            }
            __syncthreads();
            const int row = tid >> 2;                 // 0..63
            const int cc  = (tid & 3) * 32;           // 0,32,64,96
            const size_t grow = (size_t)(m0 + pass * 64 + row) * stride + col0 + cc;
            #pragma unroll
            for (int j = 0; j < 4; ++j)
                *(uint4*)(dst + grow + j * 8) = *(const uint4*)(eb + row * 136 + cc + j * 8);
            __syncthreads();
        }
    }
}

// ---- rotate (normalize(kraw) rot value) in-place bf16 + chunk-sum ----
__global__ __launch_bounds__(256)
void rotfuse_k(const unsigned short* __restrict__ qb2, unsigned short* __restrict__ valb,
               float* __restrict__ part)
{
    const int idx = blockIdx.x * 256 + threadIdx.x;   // ((b*128+ch)*256+kq)
    const int kq  = idx & 255;
    const int ch  = (idx >> 8) & 127;
    const int b   = idx >> 15;
    const int row0 = b * Ll + ch * CHL;
    float4 s = make_float4(0.f, 0.f, 0.f, 0.f);
    for (int i = 0; i < CHL; ++i) {
        const int row = row0 + i;
        const float4 q = qnorm(bq2f(*reinterpret_cast<const ushort4*>(qb2 + (size_t)row * 2048 + kq * 4)));
        ushort4* vp = reinterpret_cast<ushort4*>(valb + (size_t)row * 1024 + kq * 4);
        const float4 r = qmul(qmul(q, bq2f(*vp)), qconj(q));
        *vp = f2bq(r);
        s.x += r.x; s.y += r.y; s.z += r.z; s.w += r.w;
    }
    *reinterpret_cast<float4*>(part + (size_t)idx * 4) = s;
}

__global__ __launch_bounds__(256)
void scan2_k(float* __restrict__ part)
{
    const int idx = blockIdx.x * 256 + threadIdx.x;   // (b, kq), 1024 total
    const int kq = idx & 255, b = idx >> 8;
    float4 run = make_float4(0.f, 0.f, 0.f, 0.f);
    for (int c = 0; c < NCH; ++c) {
        float4* p = reinterpret_cast<float4*>(part + (((size_t)(b * NCH + c)) * 256 + kq) * 4);
        const float4 t = *p;
        *p = run;
        run.x += t.x; run.y += t.y; run.z += t.z; run.w += t.w;
    }
}

// ---- fused: cumsum + retrieve-rotate + /sqrt(l+1) + LayerNorm -> bf16 ----
__global__ __launch_bounds__(256)
void scan3ln_k(const unsigned short* __restrict__ rotb, const float* __restrict__ part,
               const unsigned short* __restrict__ qb2,
               const float* __restrict__ gamma, const float* __restrict__ beta,
               unsigned short* __restrict__ ln)
{
    const int kq = threadIdx.x;                     // quat 0..255
    const int ch = blockIdx.x & (NCH - 1);
    const int b  = blockIdx.x >> 7;
    const int row0 = b * Ll + ch * CHL;
    float4 run = *reinterpret_cast<const float4*>(part + (((size_t)(b * NCH + ch)) * 256 + kq) * 4);

    __shared__ float red[2][2][4];
    const int wid = kq >> 6, lane = kq & 63;
    const float4 g4 = *reinterpret_cast<const float4*>(gamma + kq * 4);
    const float4 b4 = *reinterpret_cast<const float4*>(beta  + kq * 4);

    for (int i = 0; i < CHL; ++i) {
        const int row = row0 + i;
        const float4 v = bq2f(*reinterpret_cast<const ushort4*>(rotb + (size_t)row * 1024 + kq * 4));
        run.x += v.x; run.y += v.y; run.z += v.z; run.w += v.w;

        const float4 q = qnorm(bq2f(*reinterpret_cast<const ushort4*>(qb2 + (size_t)row * 2048 + 1024 + kq * 4)));
        float4 r = qmul(qmul(qconj(q), run), q);
        const float inv = rsqrtf((float)(ch * CHL + i + 1));
        r.x *= inv; r.y *= inv; r.z *= inv; r.w *= inv;

        float s  = r.x + r.y + r.z + r.w;
        float ss = r.x * r.x + r.y * r.y + r.z * r.z + r.w * r.w;
        #pragma unroll
        for (int off = 32; off > 0; off >>= 1) {
            s  += __shfl_xor(s, off);
            ss += __shfl_xor(ss, off);
        }
        if (lane == 0) { red[i & 1][0][wid] = s; red[i & 1][1][wid] = ss; }
        __syncthreads();
        const float sum = red[i & 1][0][0] + red[i & 1][0][1] + red[i & 1][0][2] + red[i & 1][0][3];
        const float ssq = red[i & 1][1][0] + red[i & 1][1][1] + red[i & 1][1][2] + red[i & 1][1][3];
        const float mu  = sum * (1.0f / 1024.0f);
        const float var = ssq * (1.0f / 1024.0f) - mu * mu;
        const float sc  = rsqrtf(var + 1e-5f);

        float4 o;
        o.x = (r.x - mu) * sc * g4.x + b4.x;
        o.y = (r.y - mu) * sc * g4.y + b4.y;
        o.z = (r.z - mu) * sc * g4.z + b4.z;
        o.w = (r.w - mu) * sc * g4.w + b4.w;
        *reinterpret_cast<ushort4*>(ln + (size_t)row * 1024 + kq * 4) = f2bq(o);
    }
}

// ---------------- launch ----------------
extern "C" void kernel_launch(void* const* d_in, const int* in_sizes, int n_in,
                              void* d_out, int out_size, void* d_ws, size_t ws_size,
                              hipStream_t stream)
{
    const float* x     = (const float*)d_in[0];
    const float* Wk1   = (const float*)d_in[1];
    const float* bk1   = (const float*)d_in[2];
    const float* Wk2   = (const float*)d_in[3];
    const float* bk2   = (const float*)d_in[4];
    const float* Wq1   = (const float*)d_in[5];
    const float* bq1   = (const float*)d_in[6];
    const float* Wq2   = (const float*)d_in[7];
    const float* bq2   = (const float*)d_in[8];
    const float* Wv    = (const float*)d_in[9];
    const float* bv    = (const float*)d_in[10];
    const float* gamma = (const float*)d_in[11];
    const float* beta  = (const float*)d_in[12];
    const float* Wo    = (const float*)d_in[13];
    const float* bo    = (const float*)d_in[14];
    float* out = (float*)d_out;

    const size_t TD = (size_t)Mm * 1024;
    const size_t DD = (size_t)1024 * 1024;

    unsigned short* qb2   = (unsigned short*)d_ws;      // [M,2048] bf16 (64MB)
    unsigned short* xb    = qb2;                        // [M,1024] bf16 (dead before qb2 written)
    unsigned short* wcat1 = qb2 + TD;                   // [3072,1024] bf16 (dead before qb2 written)
    unsigned short* h     = qb2 + 2 * TD;               // [M,2048] bf16; ln reuses first half
    unsigned short* valb  = h + 2 * TD;                 // [M,1024] bf16 value/rotated (32MB)
    unsigned short* wcat2 = valb + TD;                  // [2048,1024] bf16 (4MB)
    unsigned short* woT   = wcat2 + 2 * DD;             // [1024,1024] bf16 (2MB)
    float*          bcat1 = (float*)(woT + DD);         // 3072
    float*          bcat2 = bcat1 + 3072;               // 2048
    float*          part  = bcat2 + 2048;               // 4*128*256*4 f32 (2MB)

    const dim3 blk(256);
    const dim3 tblk(32, 8);
    const dim3 tgrid(32, 32);

    conv_k<<<(int)(TD / 4 / 256), blk, 0, stream>>>(x, xb, (int)(TD / 4));
    wtrans_k<<<tgrid, tblk, 0, stream>>>(Wk1, wcat1);
    wtrans_k<<<tgrid, tblk, 0, stream>>>(Wq1, wcat1 + DD);
    wtrans_k<<<tgrid, tblk, 0, stream>>>(Wv,  wcat1 + 2 * DD);
    wtrans_k<<<tgrid, tblk, 0, stream>>>(Wk2, wcat2);
    wtrans_k<<<tgrid, tblk, 0, stream>>>(Wq2, wcat2 + DD);
    wtrans_k<<<tgrid, tblk, 0, stream>>>(Wo,  woT);
    bcat_k<<<12, blk, 0, stream>>>(bk1, bq1, bv, bk2, bq2, bcat1, bcat2);

    // GEMM-A: x @ [Wk1|Wq1|Wv] (N=3072) -> h (gelu bf16) + valb (bf16)
    gemm128_k<0><<<128 * 24, blk, 0, stream>>>(xb, 1024, wcat1, bcat1, nullptr, h, valb, nullptr, 3072);
    // GEMM-B: block-diag h @ {Wk2,Wq2} (N=2048) -> qb2 = [kraw|qraw] bf16
    gemm128_k<1><<<128 * 16, blk, 0, stream>>>(h, 2048, wcat2, bcat2, nullptr, qb2, nullptr, nullptr, 2048);

    rotfuse_k<<<(Bb * NCH * 256) / 256, blk, 0, stream>>>(qb2, valb, part);  // 512 blocks
    scan2_k<<<4, blk, 0, stream>>>(part);
    scan3ln_k<<<Bb * NCH, blk, 0, stream>>>(valb, part, qb2, gamma, beta, h); // ln -> h[M,1024]

    // GEMM-C: ln @ Wo + bo + x -> out (f32)
    gemm128_k<2><<<128 * 8, blk, 0, stream>>>(h, 1024, woT, bo, x, nullptr, nullptr, out, 1024);
}

// Round 15
// 454.414 us; speedup vs baseline: 1.0431x; 1.0431x over previous
//
#include <hip/hip_runtime.h>
#include <cstddef>
#include <cstdint>

static constexpr int Bb  = 4;
static constexpr int Ll  = 4096;
static constexpr int Mm  = 16384;     // B*L
static constexpr int KK  = 1024;      // GEMM K
static constexpr int NCH = 128;       // scan chunks
static constexpr int CHL = 32;        // rows per chunk

typedef __attribute__((ext_vector_type(8))) short short8;   // 8 x bf16
typedef __attribute__((ext_vector_type(4))) float f32x4;

#define AS1C(p) ((const __attribute__((address_space(1))) void*)(p))
#define AS3(p)  ((__attribute__((address_space(3))) void*)(p))

// ---------------- scalar helpers ----------------
__device__ __forceinline__ float b2f(unsigned short u) {
    union { unsigned int i; float f; } c; c.i = ((unsigned int)u) << 16; return c.f;
}
__device__ __forceinline__ unsigned short f2b(float f) {
    union { float f; unsigned int i; } c; c.f = f;
    unsigned int r = c.i + 0x7fffu + ((c.i >> 16) & 1u);
    return (unsigned short)(r >> 16);
}
__device__ __forceinline__ float4 bq2f(ushort4 u) {
    return make_float4(b2f(u.x), b2f(u.y), b2f(u.z), b2f(u.w));
}
__device__ __forceinline__ ushort4 f2bq(float4 v) {
    ushort4 o; o.x = f2b(v.x); o.y = f2b(v.y); o.z = f2b(v.z); o.w = f2b(v.w); return o;
}
__device__ __forceinline__ float4 qmul(const float4 a, const float4 b) {
    float4 r;
    r.x = a.x * b.x - a.y * b.y - a.z * b.z - a.w * b.w;
    r.y = a.x * b.y + a.y * b.x + a.z * b.w - a.w * b.z;
    r.z = a.x * b.z - a.y * b.w + a.z * b.x + a.w * b.y;
    r.w = a.x * b.w + a.y * b.z - a.z * b.y + a.w * b.x;
    return r;
}
__device__ __forceinline__ float4 qconj(const float4 a) {
    return make_float4(a.x, -a.y, -a.z, -a.w);
}
__device__ __forceinline__ float4 qnorm(const float4 a) {
    float n = sqrtf(a.x * a.x + a.y * a.y + a.z * a.z + a.w * a.w);
    float inv = 1.0f / fmaxf(n, 1e-12f);
    return make_float4(a.x * inv, a.y * inv, a.z * inv, a.w * inv);
}
// A&S 7.1.26 erf (|eps| <= 1.5e-7), branchless
__device__ __forceinline__ float gelu_fast(float v) {
    const float a = fabsf(v) * 0.70710678118654752f;
    const float t = 1.0f / (1.0f + 0.3275911f * a);
    const float p = t * (0.254829592f + t * (-0.284496736f + t * (1.421413741f
                   + t * (-1.453152027f + t * 1.061405429f))));
    const float e = __expf(-a * a);
    const float erfa = 1.0f - p * e;
    return 0.5f * v * (1.0f + copysignf(erfa, v));
}

// ---------------- fp32 -> bf16 convert ----------------
__global__ __launch_bounds__(256)
void conv_k(const float* __restrict__ src, unsigned short* __restrict__ dst, int n4)
{
    const int i = blockIdx.x * 256 + threadIdx.x;
    if (i >= n4) return;
    const float4 v = reinterpret_cast<const float4*>(src)[i];
    reinterpret_cast<ushort4*>(dst)[i] = f2bq(v);
}

// ---------------- W[K,N] fp32 -> W^T[N,K] bf16 ----------------
__global__ __launch_bounds__(256)
void wtrans_k(const float* __restrict__ src, unsigned short* __restrict__ dst)
{
    __shared__ float t[32][33];
    const int tx = threadIdx.x, ty = threadIdx.y;       // 32 x 8
    const int n0 = blockIdx.x * 32, k0 = blockIdx.y * 32;
    #pragma unroll
    for (int j = ty; j < 32; j += 8)
        t[j][tx] = src[(size_t)(k0 + j) * 1024 + n0 + tx];
    __syncthreads();
    #pragma unroll
    for (int j = ty; j < 32; j += 8)
        dst[(size_t)(n0 + j) * 1024 + k0 + tx] = f2b(t[tx][j]);
}

// ---------------- bias concat ----------------
__global__ __launch_bounds__(256)
void bcat_k(const float* __restrict__ bk1, const float* __restrict__ bq1,
            const float* __restrict__ bv,  const float* __restrict__ bk2,
            const float* __restrict__ bq2, float* __restrict__ b1,
            float* __restrict__ b2)
{
    const int i = blockIdx.x * 256 + threadIdx.x;
    if (i < 3072) b1[i] = (i < 1024) ? bk1[i] : (i < 2048 ? bq1[i - 1024] : bv[i - 2048]);
    if (i < 2048) b2[i] = (i < 1024) ? bk2[i] : bq2[i - 1024];
}

// ---- 256x128 MFMA GEMM, 128x64 per wave (intensity 42.7), BK=32, 3-buf ----
// LDS 72KB dynamic: buf c @ c*24576 {A [256r][32k] 16KB, B [128r][32k] 8KB @ +16384}.
// 2 blocks/CU (8 waves). Units: line = 2 rows x 128B, slot v=(s&7)^(line&7),
// r=2*line+(v>>2), kc=v&3  (R4/R11-verified 0-conflict packing).
// Iter t: {12 ds_read_b128 buf t%3, STAGE buf(t+2)%3 (6 gl_lds), 32 MFMA,
//          vmcnt(6) counted, barrier}.
// MODE 0: A=xb, BT=wcat1[3072,1024]; n0<2048: gelu->bf16 outH ; else ->bf16 outV
// MODE 1: A=h[M,2048] block-diag (aoff=1024 for n0>=1024) -> bf16 outH (qb2)
// MODE 2: A=ln, BT=woT -> f32 outF = acc+bias+resid
template<int MODE>
__global__ __launch_bounds__(256, 2)
void gemmbig_k(const unsigned short* __restrict__ A, int astride,
               const unsigned short* __restrict__ BT,
               const float* __restrict__ bias,
               const float* __restrict__ resid,
               unsigned short* __restrict__ outH,
               unsigned short* __restrict__ outV,
               float* __restrict__ outF,
               int Nn)
{
    extern __shared__ char smem[];   // 73728 B
    const int tid  = threadIdx.x;
    const int lane = tid & 63;
    const int w    = tid >> 6;       // 0..3
    const int wr   = w >> 1;         // 0..1 -> 128-row half
    const int wc   = w & 1;          // 0..1 -> 64-col half

    // XCD-aware bijective swizzle (gridDim.x % 8 == 0)
    const int nwg = gridDim.x;
    const int cpx = nwg >> 3;
    const int bid = blockIdx.x;
    const int swz = (bid & 7) * cpx + (bid >> 3);
    const int nTN = Nn >> 7;
    const int m0  = (swz / nTN) << 8;
    const int n0  = (swz % nTN) << 7;
    const int aoff = (MODE == 1 && n0 >= 1024) ? 1024 : 0;

    // staging source pointers (pre-swizzled to inverse of LDS layout)
    // A: 1024 slots (c2 0..3), B: 512 slots (c2 0..1); slot s = c2*256+tid.
    const unsigned short* gA[4];
    const unsigned short* gB[2];
    #pragma unroll
    for (int c2 = 0; c2 < 4; ++c2) {
        const int s = c2 * 256 + tid;
        const int line = s >> 3;
        const int v = (s & 7) ^ (line & 7);
        const int r = 2 * line + (v >> 2);
        const int kcs = v & 3;
        gA[c2] = A + (size_t)(m0 + r) * astride + aoff + kcs * 8;
        if (c2 < 2) gB[c2] = BT + (size_t)(n0 + r) * KK + kcs * 8;
    }

    auto STAGE = [&](int c, int koff) {
        #pragma unroll
        for (int c2 = 0; c2 < 4; ++c2)
            __builtin_amdgcn_global_load_lds(AS1C(gA[c2] + koff),
                AS3(smem + c * 24576 + c2 * 4096 + w * 1024), 16, 0, 0);
        #pragma unroll
        for (int c2 = 0; c2 < 2; ++c2)
            __builtin_amdgcn_global_load_lds(AS1C(gB[c2] + koff),
                AS3(smem + c * 24576 + 16384 + c2 * 4096 + w * 1024), 16, 0, 0);
    };

    // fragment read offsets (swizzled units; verified-0-conflict pattern)
    const int kc4 = lane >> 4;      // k-chunk 0..3
    const int rl  = lane & 15;
    int offA[8], offB[4];
    #pragma unroll
    for (int mi = 0; mi < 8; ++mi) {
        const int r = wr * 128 + mi * 16 + rl;
        offA[mi] = (r >> 1) * 128 + (((((r & 1) << 2) | kc4) ^ ((r >> 1) & 7)) << 4);
    }
    #pragma unroll
    for (int ni = 0; ni < 4; ++ni) {
        const int r = wc * 64 + ni * 16 + rl;
        offB[ni] = 16384 + (r >> 1) * 128 + (((((r & 1) << 2) | kc4) ^ ((r >> 1) & 7)) << 4);
    }

    f32x4 acc[8][4] = {};

    // iteration: 12 ds_read first, stage tile t+2 into sb, 32 MFMA, counted wait.
    auto ITER = [&](int rb, int sb, int ks, int vm) {
        const int cb = rb * 24576;
        short8 af[8], bf[4];
        #pragma unroll
        for (int mi = 0; mi < 8; ++mi) af[mi] = *(const short8*)(smem + cb + offA[mi]);
        #pragma unroll
        for (int ni = 0; ni < 4; ++ni) bf[ni] = *(const short8*)(smem + cb + offB[ni]);
        if (ks >= 0) STAGE(sb, ks);
        #pragma unroll
        for (int mi = 0; mi < 8; ++mi)
            #pragma unroll
            for (int ni = 0; ni < 4; ++ni)
                acc[mi][ni] = __builtin_amdgcn_mfma_f32_16x16x32_bf16(af[mi], bf[ni], acc[mi][ni], 0, 0, 0);
        if (vm == 6)      asm volatile("s_waitcnt vmcnt(6)" ::: "memory");
        else if (vm == 0) asm volatile("s_waitcnt vmcnt(0)" ::: "memory");
        if (vm >= 0) __builtin_amdgcn_s_barrier();
    };

    // prologue: stage tiles 0,1 into bufs 0,1 ; drain tile0 (oldest 6), publish
    STAGE(0, 0);
    STAGE(1, 32);
    asm volatile("s_waitcnt vmcnt(6)" ::: "memory");
    __builtin_amdgcn_s_barrier();

    // steady state: t = 0..29 (stage t+2), unrolled x3 for static buf indices
    #pragma unroll 1
    for (int t0 = 0; t0 < 30; t0 += 3) {
        ITER(0, 2, (t0 + 2) * 32, 6);
        ITER(1, 0, (t0 + 3) * 32, 6);
        ITER(2, 1, (t0 + 4) * 32, 6);
    }
    ITER(0, 0, -1, 0);    // t=30: read buf0, drain tile31
    ITER(1, 0, -1, -1);   // t=31: read buf1, no wait
    __syncthreads();      // retire LDS reads before epilogue reuses smem

    // ---- epilogue: C layout col = lane&15 (+16*ni), row = kc4*4 + rr (+16*mi) ----
    const int colb = n0 + wc * 64 + rl;
    float bv[4];
    #pragma unroll
    for (int ni = 0; ni < 4; ++ni) bv[ni] = bias[colb + ni * 16];

    if (MODE == 2) {
        const int rowb = m0 + wr * 128 + kc4 * 4;
        #pragma unroll
        for (int ni = 0; ni < 4; ++ni) {
            const int col = colb + ni * 16;
            #pragma unroll
            for (int mi = 0; mi < 8; ++mi) {
                #pragma unroll
                for (int rr = 0; rr < 4; ++rr) {
                    const int row = rowb + mi * 16 + rr;
                    const size_t ix = (size_t)row * 1024 + col;
                    outF[ix] = acc[mi][ni][rr] + bv[ni] + resid[ix];
                }
            }
        }
    } else {
        const bool dogelu = (MODE == 0) && (n0 < 2048);
        unsigned short* dst;
        int stride, col0;
        if (MODE == 0 && n0 >= 2048) { dst = outV; stride = 1024; col0 = n0 - 2048; }
        else                         { dst = outH; stride = 2048; col0 = n0; }
        // stage 64 rows at a time through LDS for coalesced 16B stores, 4 passes
        unsigned short* eb = (unsigned short*)smem;   // [64][136] = 17.4 KB
        #pragma unroll
        for (int pass = 0; pass < 4; ++pass) {
            if (wr == (pass >> 1)) {
                const int mib = (pass & 1) * 4;
                #pragma unroll
                for (int ni = 0; ni < 4; ++ni) {
                    const int col = wc * 64 + ni * 16 + rl;
                    #pragma unroll
                    for (int mi = 0; mi < 4; ++mi) {
                        #pragma unroll
                        for (int rr = 0; rr < 4; ++rr) {
                            float v = acc[mib + mi][ni][rr] + bv[ni];
                            if (dogelu) v = gelu_fast(v);
                            eb[(mi * 16 + kc4 * 4 + rr) * 136 + col] = f2b(v);
                        }
                    }
                }
            }
            __syncthreads();
            const int row = tid >> 2;                 // 0..63
            const int cc  = (tid & 3) * 32;           // 0,32,64,96
            const size_t grow = (size_t)(m0 + pass * 64 + row) * stride + col0 + cc;
            #pragma unroll
            for (int j = 0; j < 4; ++j)
                *(uint4*)(dst + grow + j * 8) = *(const uint4*)(eb + row * 136 + cc + j * 8);
            __syncthreads();
        }
    }
}

// ---- rotate (normalize(kraw) rot value) in-place bf16 + chunk-sum ----
__global__ __launch_bounds__(256)
void rotfuse_k(const unsigned short* __restrict__ qb2, unsigned short* __restrict__ valb,
               float* __restrict__ part)
{
    const int idx = blockIdx.x * 256 + threadIdx.x;   // ((b*128+ch)*256+kq)
    const int kq  = idx & 255;
    const int ch  = (idx >> 8) & 127;
    const int b   = idx >> 15;
    const int row0 = b * Ll + ch * CHL;
    float4 s = make_float4(0.f, 0.f, 0.f, 0.f);
    for (int i = 0; i < CHL; ++i) {
        const int row = row0 + i;
        const float4 q = qnorm(bq2f(*reinterpret_cast<const ushort4*>(qb2 + (size_t)row * 2048 + kq * 4)));
        ushort4* vp = reinterpret_cast<ushort4*>(valb + (size_t)row * 1024 + kq * 4);
        const float4 r = qmul(qmul(q, bq2f(*vp)), qconj(q));
        *vp = f2bq(r);
        s.x += r.x; s.y += r.y; s.z += r.z; s.w += r.w;
    }
    *reinterpret_cast<float4*>(part + (size_t)idx * 4) = s;
}

__global__ __launch_bounds__(256)
void scan2_k(float* __restrict__ part)
{
    const int idx = blockIdx.x * 256 + threadIdx.x;   // (b, kq), 1024 total
    const int kq = idx & 255, b = idx >> 8;
    float4 run = make_float4(0.f, 0.f, 0.f, 0.f);
    for (int c = 0; c < NCH; ++c) {
        float4* p = reinterpret_cast<float4*>(part + (((size_t)(b * NCH + c)) * 256 + kq) * 4);
        const float4 t = *p;
        *p = run;
        run.x += t.x; run.y += t.y; run.z += t.z; run.w += t.w;
    }
}

// ---- fused: cumsum + retrieve-rotate + /sqrt(l+1) + LayerNorm -> bf16 ----
__global__ __launch_bounds__(256)
void scan3ln_k(const unsigned short* __restrict__ rotb, const float* __restrict__ part,
               const unsigned short* __restrict__ qb2,
               const float* __restrict__ gamma, const float* __restrict__ beta,
               unsigned short* __restrict__ ln)
{
    const int kq = threadIdx.x;                     // quat 0..255
    const int ch = blockIdx.x & (NCH - 1);
    const int b  = blockIdx.x >> 7;
    const int row0 = b * Ll + ch * CHL;
    float4 run = *reinterpret_cast<const float4*>(part + (((size_t)(b * NCH + ch)) * 256 + kq) * 4);

    __shared__ float red[2][2][4];
    const int wid = kq >> 6, lane = kq & 63;
    const float4 g4 = *reinterpret_cast<const float4*>(gamma + kq * 4);
    const float4 b4 = *reinterpret_cast<const float4*>(beta  + kq * 4);

    for (int i = 0; i < CHL; ++i) {
        const int row = row0 + i;
        const float4 v = bq2f(*reinterpret_cast<const ushort4*>(rotb + (size_t)row * 1024 + kq * 4));
        run.x += v.x; run.y += v.y; run.z += v.z; run.w += v.w;

        const float4 q = qnorm(bq2f(*reinterpret_cast<const ushort4*>(qb2 + (size_t)row * 2048 + 1024 + kq * 4)));
        float4 r = qmul(qmul(qconj(q), run), q);
        const float inv = rsqrtf((float)(ch * CHL + i + 1));
        r.x *= inv; r.y *= inv; r.z *= inv; r.w *= inv;

        float s  = r.x + r.y + r.z + r.w;
        float ss = r.x * r.x + r.y * r.y + r.z * r.z + r.w * r.w;
        #pragma unroll
        for (int off = 32; off > 0; off >>= 1) {
            s  += __shfl_xor(s, off);
            ss += __shfl_xor(ss, off);
        }
        if (lane == 0) { red[i & 1][0][wid] = s; red[i & 1][1][wid] = ss; }
        __syncthreads();
        const float sum = red[i & 1][0][0] + red[i & 1][0][1] + red[i & 1][0][2] + red[i & 1][0][3];
        const float ssq = red[i & 1][1][0] + red[i & 1][1][1] + red[i & 1][1][2] + red[i & 1][1][3];
        const float mu  = sum * (1.0f / 1024.0f);
        const float var = ssq * (1.0f / 1024.0f) - mu * mu;
        const float sc  = rsqrtf(var + 1e-5f);

        float4 o;
        o.x = (r.x - mu) * sc * g4.x + b4.x;
        o.y = (r.y - mu) * sc * g4.y + b4.y;
        o.z = (r.z - mu) * sc * g4.z + b4.z;
        o.w = (r.w - mu) * sc * g4.w + b4.w;
        *reinterpret_cast<ushort4*>(ln + (size_t)row * 1024 + kq * 4) = f2bq(o);
    }
}

// ---------------- launch ----------------
extern "C" void kernel_launch(void* const* d_in, const int* in_sizes, int n_in,
                              void* d_out, int out_size, void* d_ws, size_t ws_size,
                              hipStream_t stream)
{
    const float* x     = (const float*)d_in[0];
    const float* Wk1   = (const float*)d_in[1];
    const float* bk1   = (const float*)d_in[2];
    const float* Wk2   = (const float*)d_in[3];
    const float* bk2   = (const float*)d_in[4];
    const float* Wq1   = (const float*)d_in[5];
    const float* bq1   = (const float*)d_in[6];
    const float* Wq2   = (const float*)d_in[7];
    const float* bq2   = (const float*)d_in[8];
    const float* Wv    = (const float*)d_in[9];
    const float* bv    = (const float*)d_in[10];
    const float* gamma = (const float*)d_in[11];
    const float* beta  = (const float*)d_in[12];
    const float* Wo    = (const float*)d_in[13];
    const float* bo    = (const float*)d_in[14];
    float* out = (float*)d_out;

    const size_t TD = (size_t)Mm * 1024;
    const size_t DD = (size_t)1024 * 1024;

    unsigned short* qb2   = (unsigned short*)d_ws;      // [M,2048] bf16 (64MB)
    unsigned short* xb    = qb2;                        // [M,1024] bf16 (dead before qb2 written)
    unsigned short* wcat1 = qb2 + TD;                   // [3072,1024] bf16 (dead before qb2 written)
    unsigned short* h     = qb2 + 2 * TD;               // [M,2048] bf16; ln reuses first half
    unsigned short* valb  = h + 2 * TD;                 // [M,1024] bf16 value/rotated (32MB)
    unsigned short* wcat2 = valb + TD;                  // [2048,1024] bf16 (4MB)
    unsigned short* woT   = wcat2 + 2 * DD;             // [1024,1024] bf16 (2MB)
    float*          bcat1 = (float*)(woT + DD);         // 3072
    float*          bcat2 = bcat1 + 3072;               // 2048
    float*          part  = bcat2 + 2048;               // 4*128*256*4 f32 (2MB)

    const dim3 blk(256);
    const dim3 tblk(32, 8);
    const dim3 tgrid(32, 32);

    (void)hipFuncSetAttribute((const void*)gemmbig_k<0>, hipFuncAttributeMaxDynamicSharedMemorySize, 73728);
    (void)hipFuncSetAttribute((const void*)gemmbig_k<1>, hipFuncAttributeMaxDynamicSharedMemorySize, 73728);
    (void)hipFuncSetAttribute((const void*)gemmbig_k<2>, hipFuncAttributeMaxDynamicSharedMemorySize, 73728);

    conv_k<<<(int)(TD / 4 / 256), blk, 0, stream>>>(x, xb, (int)(TD / 4));
    wtrans_k<<<tgrid, tblk, 0, stream>>>(Wk1, wcat1);
    wtrans_k<<<tgrid, tblk, 0, stream>>>(Wq1, wcat1 + DD);
    wtrans_k<<<tgrid, tblk, 0, stream>>>(Wv,  wcat1 + 2 * DD);
    wtrans_k<<<tgrid, tblk, 0, stream>>>(Wk2, wcat2);
    wtrans_k<<<tgrid, tblk, 0, stream>>>(Wq2, wcat2 + DD);
    wtrans_k<<<tgrid, tblk, 0, stream>>>(Wo,  woT);
    bcat_k<<<12, blk, 0, stream>>>(bk1, bq1, bv, bk2, bq2, bcat1, bcat2);

    // GEMM-A: x @ [Wk1|Wq1|Wv] (N=3072) -> h (gelu bf16) + valb (bf16); 64x24 tiles
    gemmbig_k<0><<<64 * 24, blk, 73728, stream>>>(xb, 1024, wcat1, bcat1, nullptr, h, valb, nullptr, 3072);
    // GEMM-B: block-diag h @ {Wk2,Wq2} (N=2048) -> qb2 = [kraw|qraw] bf16; 64x16 tiles
    gemmbig_k<1><<<64 * 16, blk, 73728, stream>>>(h, 2048, wcat2, bcat2, nullptr, qb2, nullptr, nullptr, 2048);

    rotfuse_k<<<(Bb * NCH * 256) / 256, blk, 0, stream>>>(qb2, valb, part);  // 512 blocks
    scan2_k<<<4, blk, 0, stream>>>(part);
    scan3ln_k<<<Bb * NCH, blk, 0, stream>>>(valb, part, qb2, gamma, beta, h); // ln -> h[M,1024]

    // GEMM-C: ln @ Wo + bo + x -> out (f32); 64x8 tiles
    gemmbig_k<2><<<64 * 8, blk, 73728, stream>>>(h, 1024, woT, bo, x, nullptr, nullptr, out, 1024);
}

// Round 16
// 418.217 us; speedup vs baseline: 1.1334x; 1.0866x over previous
//
#include <hip/hip_runtime.h>
#include <cstddef>
#include <cstdint>

static constexpr int Bb  = 4;
static constexpr int Ll  = 4096;
static constexpr int Mm  = 16384;     // B*L
static constexpr int KK  = 1024;      // GEMM K
static constexpr int NCH = 128;       // scan chunks
static constexpr int CHL = 32;        // rows per chunk

typedef __attribute__((ext_vector_type(8))) short short8;   // 8 x bf16
typedef __attribute__((ext_vector_type(4))) float f32x4;

#define AS1C(p) ((const __attribute__((address_space(1))) void*)(p))
#define AS3(p)  ((__attribute__((address_space(3))) void*)(p))

// ---------------- scalar helpers ----------------
__device__ __forceinline__ float b2f(unsigned short u) {
    union { unsigned int i; float f; } c; c.i = ((unsigned int)u) << 16; return c.f;
}
__device__ __forceinline__ unsigned short f2b(float f) {
    union { float f; unsigned int i; } c; c.f = f;
    unsigned int r = c.i + 0x7fffu + ((c.i >> 16) & 1u);
    return (unsigned short)(r >> 16);
}
__device__ __forceinline__ float4 bq2f(ushort4 u) {
    return make_float4(b2f(u.x), b2f(u.y), b2f(u.z), b2f(u.w));
}
__device__ __forceinline__ ushort4 f2bq(float4 v) {
    ushort4 o; o.x = f2b(v.x); o.y = f2b(v.y); o.z = f2b(v.z); o.w = f2b(v.w); return o;
}
__device__ __forceinline__ float4 qmul(const float4 a, const float4 b) {
    float4 r;
    r.x = a.x * b.x - a.y * b.y - a.z * b.z - a.w * b.w;
    r.y = a.x * b.y + a.y * b.x + a.z * b.w - a.w * b.z;
    r.z = a.x * b.z - a.y * b.w + a.z * b.x + a.w * b.y;
    r.w = a.x * b.w + a.y * b.z - a.z * b.y + a.w * b.x;
    return r;
}
__device__ __forceinline__ float4 qconj(const float4 a) {
    return make_float4(a.x, -a.y, -a.z, -a.w);
}
__device__ __forceinline__ float4 qnorm(const float4 a) {
    float n = sqrtf(a.x * a.x + a.y * a.y + a.z * a.z + a.w * a.w);
    float inv = 1.0f / fmaxf(n, 1e-12f);
    return make_float4(a.x * inv, a.y * inv, a.z * inv, a.w * inv);
}
// A&S 7.1.26 erf (|eps| <= 1.5e-7), branchless
__device__ __forceinline__ float gelu_fast(float v) {
    const float a = fabsf(v) * 0.70710678118654752f;
    const float t = 1.0f / (1.0f + 0.3275911f * a);
    const float p = t * (0.254829592f + t * (-0.284496736f + t * (1.421413741f
                   + t * (-1.453152027f + t * 1.061405429f))));
    const float e = __expf(-a * a);
    const float erfa = 1.0f - p * e;
    return 0.5f * v * (1.0f + copysignf(erfa, v));
}

// ---------------- fp32 -> bf16 convert ----------------
__global__ __launch_bounds__(256)
void conv_k(const float* __restrict__ src, unsigned short* __restrict__ dst, int n4)
{
    const int i = blockIdx.x * 256 + threadIdx.x;
    if (i >= n4) return;
    const float4 v = reinterpret_cast<const float4*>(src)[i];
    reinterpret_cast<ushort4*>(dst)[i] = f2bq(v);
}

// ---------------- W[K,N] fp32 -> W^T[N,K] bf16 ----------------
__global__ __launch_bounds__(256)
void wtrans_k(const float* __restrict__ src, unsigned short* __restrict__ dst)
{
    __shared__ float t[32][33];
    const int tx = threadIdx.x, ty = threadIdx.y;       // 32 x 8
    const int n0 = blockIdx.x * 32, k0 = blockIdx.y * 32;
    #pragma unroll
    for (int j = ty; j < 32; j += 8)
        t[j][tx] = src[(size_t)(k0 + j) * 1024 + n0 + tx];
    __syncthreads();
    #pragma unroll
    for (int j = ty; j < 32; j += 8)
        dst[(size_t)(n0 + j) * 1024 + k0 + tx] = f2b(t[tx][j]);
}

// ---------------- bias concat ----------------
__global__ __launch_bounds__(256)
void bcat_k(const float* __restrict__ bk1, const float* __restrict__ bq1,
            const float* __restrict__ bv,  const float* __restrict__ bk2,
            const float* __restrict__ bq2, float* __restrict__ b1,
            float* __restrict__ b2)
{
    const int i = blockIdx.x * 256 + threadIdx.x;
    if (i < 3072) b1[i] = (i < 1024) ? bk1[i] : (i < 2048 ? bq1[i - 1024] : bv[i - 2048]);
    if (i < 2048) b2[i] = (i < 1024) ? bk2[i] : bq2[i - 1024];
}

// ---- 128x128 MFMA GEMM, BK=32, 3-buf depth-2 prefetch, 1 barrier/iter (R9 best) ----
// LDS 48KB static: buf c @ c*16384 {A 8KB, B 8KB @ +8192}. 3 blocks/CU.
// Unit = [128 rows][32 k] bf16 packed 64 lines x 128B, slot-XOR swizzle (0 conflicts).
// Iter t: {STAGE buf(t+2)%3 (4 gl_lds), 8 ds_read_b128 buf t%3, 16 MFMA+setprio,
//          vmcnt(4) (counted — tile t+1 stays in flight), barrier}.
// MODE 0: A=xb, BT=wcat1[3072,1024]; n0<2048: gelu->bf16 outH ; else ->bf16 outV
// MODE 1: A=h[M,2048] block-diag (aoff=1024 for n0>=1024) -> bf16 outH (qb2)
// MODE 2: A=ln, BT=woT -> f32 outF = acc+bias+resid
template<int MODE>
__global__ __launch_bounds__(256, 3)
void gemm128_k(const unsigned short* __restrict__ A, int astride,
               const unsigned short* __restrict__ BT,
               const float* __restrict__ bias,
               const float* __restrict__ resid,
               unsigned short* __restrict__ outH,
               unsigned short* __restrict__ outV,
               float* __restrict__ outF,
               int Nn)
{
    __shared__ char smem[49152];
    const int tid  = threadIdx.x;
    const int lane = tid & 63;
    const int w    = tid >> 6;       // 0..3
    const int wr   = w >> 1;         // 0..1 -> 64-row half
    const int wc   = w & 1;          // 0..1 -> 64-col half

    // XCD-aware bijective swizzle (gridDim.x % 8 == 0)
    const int nwg = gridDim.x;
    const int cpx = nwg >> 3;
    const int bid = blockIdx.x;
    const int swz = (bid & 7) * cpx + (bid >> 3);
    const int nTN = Nn >> 7;
    const int m0  = (swz / nTN) << 7;
    const int n0  = (swz % nTN) << 7;
    const int aoff = (MODE == 1 && n0 >= 1024) ? 1024 : 0;

    // staging source: slot s = c2*256+tid; line=s>>3; u=(s&7)^(line&7);
    // r=2*line+(u>>2); kc=u&3  (LDS holds swizzled layout, 0-conflict reads)
    const unsigned short* gA[2];
    const unsigned short* gB[2];
    #pragma unroll
    for (int c2 = 0; c2 < 2; ++c2) {
        const int s = c2 * 256 + tid;
        const int line = s >> 3;
        const int u = (s & 7) ^ (line & 7);
        const int r = 2 * line + (u >> 2);
        const int kcs = u & 3;
        gA[c2] = A + (size_t)(m0 + r) * astride + aoff + kcs * 8;
        gB[c2] = BT + (size_t)(n0 + r) * KK + kcs * 8;
    }

    auto STAGE = [&](int c, int koff) {
        #pragma unroll
        for (int c2 = 0; c2 < 2; ++c2)
            __builtin_amdgcn_global_load_lds(AS1C(gA[c2] + koff),
                AS3(smem + c * 16384 + c2 * 4096 + w * 1024), 16, 0, 0);
        #pragma unroll
        for (int c2 = 0; c2 < 2; ++c2)
            __builtin_amdgcn_global_load_lds(AS1C(gB[c2] + koff),
                AS3(smem + c * 16384 + 8192 + c2 * 4096 + w * 1024), 16, 0, 0);
    };

    // fragment read offsets within a unit (swizzled; measured 0-conflict)
    const int kc4 = lane >> 4;      // k-chunk 0..3
    const int rl  = lane & 15;
    int offA[4], offB[4];
    #pragma unroll
    for (int mi = 0; mi < 4; ++mi) {
        const int r = wr * 64 + mi * 16 + rl;
        offA[mi] = (r >> 1) * 128 + (((((r & 1) << 2) | kc4) ^ ((r >> 1) & 7)) << 4);
    }
    #pragma unroll
    for (int ni = 0; ni < 4; ++ni) {
        const int r = wc * 64 + ni * 16 + rl;
        offB[ni] = 8192 + (r >> 1) * 128 + (((((r & 1) << 2) | kc4) ^ ((r >> 1) & 7)) << 4);
    }

    f32x4 acc[4][4] = {};

    // iteration body: stage tile t+2 into sb FIRST, then read buf rb, MFMA.
    // vm: 4 -> vmcnt(4); 0 -> vmcnt(0); -1 -> none. One barrier per iter.
    auto ITER = [&](int rb, int sb, int ks, int vm) {
        if (ks >= 0) STAGE(sb, ks);
        const int cb = rb * 16384;
        short8 af[4], bf[4];
        #pragma unroll
        for (int mi = 0; mi < 4; ++mi) af[mi] = *(const short8*)(smem + cb + offA[mi]);
        #pragma unroll
        for (int ni = 0; ni < 4; ++ni) bf[ni] = *(const short8*)(smem + cb + offB[ni]);
        __builtin_amdgcn_s_setprio(1);
        #pragma unroll
        for (int mi = 0; mi < 4; ++mi)
            #pragma unroll
            for (int ni = 0; ni < 4; ++ni)
                acc[mi][ni] = __builtin_amdgcn_mfma_f32_16x16x32_bf16(af[mi], bf[ni], acc[mi][ni], 0, 0, 0);
        __builtin_amdgcn_s_setprio(0);
        if (vm == 4)      asm volatile("s_waitcnt vmcnt(4)" ::: "memory");
        else if (vm == 0) asm volatile("s_waitcnt vmcnt(0)" ::: "memory");
        if (vm >= 0) __builtin_amdgcn_s_barrier();
    };

    // prologue: stage tiles 0,1 into bufs 0,1 ; drain tile0 (oldest 4), publish
    STAGE(0, 0);
    STAGE(1, 32);
    asm volatile("s_waitcnt vmcnt(4)" ::: "memory");
    __builtin_amdgcn_s_barrier();

    // steady state: t = 0..29 (stage t+2), unrolled x3 for static buf indices
    #pragma unroll 1
    for (int t0 = 0; t0 < 30; t0 += 3) {
        ITER(0, 2, (t0 + 2) * 32, 4);
        ITER(1, 0, (t0 + 3) * 32, 4);
        ITER(2, 1, (t0 + 4) * 32, 4);
    }
    ITER(0, 0, -1, 0);    // t=30: read buf0, drain tile31
    ITER(1, 0, -1, -1);   // t=31: read buf1, no wait
    __syncthreads();      // retire LDS reads before epilogue reuses smem

    // ---- epilogue: C layout col = lane&15 (+16*ni), row = kc4*4 + rr (+16*mi) ----
    const int colb = n0 + wc * 64 + rl;
    float bv[4];
    #pragma unroll
    for (int ni = 0; ni < 4; ++ni) bv[ni] = bias[colb + ni * 16];

    if (MODE == 2) {
        const int rowb = m0 + wr * 64 + kc4 * 4;
        #pragma unroll
        for (int ni = 0; ni < 4; ++ni) {
            const int col = colb + ni * 16;
            #pragma unroll
            for (int mi = 0; mi < 4; ++mi) {
                #pragma unroll
                for (int rr = 0; rr < 4; ++rr) {
                    const int row = rowb + mi * 16 + rr;
                    const size_t ix = (size_t)row * 1024 + col;
                    outF[ix] = acc[mi][ni][rr] + bv[ni] + resid[ix];
                }
            }
        }
    } else {
        const bool dogelu = (MODE == 0) && (n0 < 2048);
        unsigned short* dst;
        int stride, col0;
        if (MODE == 0 && n0 >= 2048) { dst = outV; stride = 1024; col0 = n0 - 2048; }
        else                         { dst = outH; stride = 2048; col0 = n0; }
        // stage 64 rows at a time through LDS for coalesced 16B stores
        unsigned short* eb = (unsigned short*)smem;   // [64][136] = 17.4 KB
        #pragma unroll
        for (int pass = 0; pass < 2; ++pass) {
            if (wr == pass) {
                #pragma unroll
                for (int ni = 0; ni < 4; ++ni) {
                    const int col = wc * 64 + ni * 16 + rl;
                    #pragma unroll
                    for (int mi = 0; mi < 4; ++mi) {
                        #pragma unroll
                        for (int rr = 0; rr < 4; ++rr) {
                            float v = acc[mi][ni][rr] + bv[ni];
                            if (dogelu) v = gelu_fast(v);
                            eb[(mi * 16 + kc4 * 4 + rr) * 136 + col] = f2b(v);
                        }
                    }
                }
            }
            __syncthreads();
            const int row = tid >> 2;                 // 0..63
            const int cc  = (tid & 3) * 32;           // 0,32,64,96
            const size_t grow = (size_t)(m0 + pass * 64 + row) * stride + col0 + cc;
            #pragma unroll
            for (int j = 0; j < 4; ++j)
                *(uint4*)(dst + grow + j * 8) = *(const uint4*)(eb + row * 136 + cc + j * 8);
            __syncthreads();
        }
    }
}

// ---- rotate (normalize(kraw) rot value) in-place bf16 + chunk-sum ----
__global__ __launch_bounds__(256)
void rotfuse_k(const unsigned short* __restrict__ qb2, unsigned short* __restrict__ valb,
               float* __restrict__ part)
{
    const int idx = blockIdx.x * 256 + threadIdx.x;   // ((b*128+ch)*256+kq)
    const int kq  = idx & 255;
    const int ch  = (idx >> 8) & 127;
    const int b   = idx >> 15;
    const int row0 = b * Ll + ch * CHL;
    float4 s = make_float4(0.f, 0.f, 0.f, 0.f);
    for (int i = 0; i < CHL; ++i) {
        const int row = row0 + i;
        const float4 q = qnorm(bq2f(*reinterpret_cast<const ushort4*>(qb2 + (size_t)row * 2048 + kq * 4)));
        ushort4* vp = reinterpret_cast<ushort4*>(valb + (size_t)row * 1024 + kq * 4);
        const float4 r = qmul(qmul(q, bq2f(*vp)), qconj(q));
        *vp = f2bq(r);
        s.x += r.x; s.y += r.y; s.z += r.z; s.w += r.w;
    }
    *reinterpret_cast<float4*>(part + (size_t)idx * 4) = s;
}

__global__ __launch_bounds__(256)
void scan2_k(float* __restrict__ part)
{
    const int idx = blockIdx.x * 256 + threadIdx.x;   // (b, kq), 1024 total
    const int kq = idx & 255, b = idx >> 8;
    float4 run = make_float4(0.f, 0.f, 0.f, 0.f);
    for (int c = 0; c < NCH; ++c) {
        float4* p = reinterpret_cast<float4*>(part + (((size_t)(b * NCH + c)) * 256 + kq) * 4);
        const float4 t = *p;
        *p = run;
        run.x += t.x; run.y += t.y; run.z += t.z; run.w += t.w;
    }
}

// ---- fused: cumsum + retrieve-rotate + /sqrt(l+1) + LayerNorm -> bf16 ----
__global__ __launch_bounds__(256)
void scan3ln_k(const unsigned short* __restrict__ rotb, const float* __restrict__ part,
               const unsigned short* __restrict__ qb2,
               const float* __restrict__ gamma, const float* __restrict__ beta,
               unsigned short* __restrict__ ln)
{
    const int kq = threadIdx.x;                     // quat 0..255
    const int ch = blockIdx.x & (NCH - 1);
    const int b  = blockIdx.x >> 7;
    const int row0 = b * Ll + ch * CHL;
    float4 run = *reinterpret_cast<const float4*>(part + (((size_t)(b * NCH + ch)) * 256 + kq) * 4);

    __shared__ float red[2][2][4];
    const int wid = kq >> 6, lane = kq & 63;
    const float4 g4 = *reinterpret_cast<const float4*>(gamma + kq * 4);
    const float4 b4 = *reinterpret_cast<const float4*>(beta  + kq * 4);

    for (int i = 0; i < CHL; ++i) {
        const int row = row0 + i;
        const float4 v = bq2f(*reinterpret_cast<const ushort4*>(rotb + (size_t)row * 1024 + kq * 4));
        run.x += v.x; run.y += v.y; run.z += v.z; run.w += v.w;

        const float4 q = qnorm(bq2f(*reinterpret_cast<const ushort4*>(qb2 + (size_t)row * 2048 + 1024 + kq * 4)));
        float4 r = qmul(qmul(qconj(q), run), q);
        const float inv = rsqrtf((float)(ch * CHL + i + 1));
        r.x *= inv; r.y *= inv; r.z *= inv; r.w *= inv;

        float s  = r.x + r.y + r.z + r.w;
        float ss = r.x * r.x + r.y * r.y + r.z * r.z + r.w * r.w;
        #pragma unroll
        for (int off = 32; off > 0; off >>= 1) {
            s  += __shfl_xor(s, off);
            ss += __shfl_xor(ss, off);
        }
        if (lane == 0) { red[i & 1][0][wid] = s; red[i & 1][1][wid] = ss; }
        __syncthreads();
        const float sum = red[i & 1][0][0] + red[i & 1][0][1] + red[i & 1][0][2] + red[i & 1][0][3];
        const float ssq = red[i & 1][1][0] + red[i & 1][1][1] + red[i & 1][1][2] + red[i & 1][1][3];
        const float mu  = sum * (1.0f / 1024.0f);
        const float var = ssq * (1.0f / 1024.0f) - mu * mu;
        const float sc  = rsqrtf(var + 1e-5f);

        float4 o;
        o.x = (r.x - mu) * sc * g4.x + b4.x;
        o.y = (r.y - mu) * sc * g4.y + b4.y;
        o.z = (r.z - mu) * sc * g4.z + b4.z;
        o.w = (r.w - mu) * sc * g4.w + b4.w;
        *reinterpret_cast<ushort4*>(ln + (size_t)row * 1024 + kq * 4) = f2bq(o);
    }
}

// ---------------- launch ----------------
extern "C" void kernel_launch(void* const* d_in, const int* in_sizes, int n_in,
                              void* d_out, int out_size, void* d_ws, size_t ws_size,
                              hipStream_t stream)
{
    const float* x     = (const float*)d_in[0];
    const float* Wk1   = (const float*)d_in[1];
    const float* bk1   = (const float*)d_in[2];
    const float* Wk2   = (const float*)d_in[3];
    const float* bk2   = (const float*)d_in[4];
    const float* Wq1   = (const float*)d_in[5];
    const float* bq1   = (const float*)d_in[6];
    const float* Wq2   = (const float*)d_in[7];
    const float* bq2   = (const float*)d_in[8];
    const float* Wv    = (const float*)d_in[9];
    const float* bv    = (const float*)d_in[10];
    const float* gamma = (const float*)d_in[11];
    const float* beta  = (const float*)d_in[12];
    const float* Wo    = (const float*)d_in[13];
    const float* bo    = (const float*)d_in[14];
    float* out = (float*)d_out;

    const size_t TD = (size_t)Mm * 1024;
    const size_t DD = (size_t)1024 * 1024;

    unsigned short* qb2   = (unsigned short*)d_ws;      // [M,2048] bf16 (64MB)
    unsigned short* xb    = qb2;                        // [M,1024] bf16 (dead before qb2 written)
    unsigned short* wcat1 = qb2 + TD;                   // [3072,1024] bf16 (dead before qb2 written)
    unsigned short* h     = qb2 + 2 * TD;               // [M,2048] bf16; ln reuses first half
    unsigned short* valb  = h + 2 * TD;                 // [M,1024] bf16 value/rotated (32MB)
    unsigned short* wcat2 = valb + TD;                  // [2048,1024] bf16 (4MB)
    unsigned short* woT   = wcat2 + 2 * DD;             // [1024,1024] bf16 (2MB)
    float*          bcat1 = (float*)(woT + DD);         // 3072
    float*          bcat2 = bcat1 + 3072;               // 2048
    float*          part  = bcat2 + 2048;               // 4*128*256*4 f32 (2MB)

    const dim3 blk(256);
    const dim3 tblk(32, 8);
    const dim3 tgrid(32, 32);

    conv_k<<<(int)(TD / 4 / 256), blk, 0, stream>>>(x, xb, (int)(TD / 4));
    wtrans_k<<<tgrid, tblk, 0, stream>>>(Wk1, wcat1);
    wtrans_k<<<tgrid, tblk, 0, stream>>>(Wq1, wcat1 + DD);
    wtrans_k<<<tgrid, tblk, 0, stream>>>(Wv,  wcat1 + 2 * DD);
    wtrans_k<<<tgrid, tblk, 0, stream>>>(Wk2, wcat2);
    wtrans_k<<<tgrid, tblk, 0, stream>>>(Wq2, wcat2 + DD);
    wtrans_k<<<tgrid, tblk, 0, stream>>>(Wo,  woT);
    bcat_k<<<12, blk, 0, stream>>>(bk1, bq1, bv, bk2, bq2, bcat1, bcat2);

    // GEMM-A: x @ [Wk1|Wq1|Wv] (N=3072) -> h (gelu bf16) + valb (bf16)
    gemm128_k<0><<<128 * 24, blk, 0, stream>>>(xb, 1024, wcat1, bcat1, nullptr, h, valb, nullptr, 3072);
    // GEMM-B: block-diag h @ {Wk2,Wq2} (N=2048) -> qb2 = [kraw|qraw] bf16
    gemm128_k<1><<<128 * 16, blk, 0, stream>>>(h, 2048, wcat2, bcat2, nullptr, qb2, nullptr, nullptr, 2048);

    rotfuse_k<<<(Bb * NCH * 256) / 256, blk, 0, stream>>>(qb2, valb, part);  // 512 blocks
    scan2_k<<<4, blk, 0, stream>>>(part);
    scan3ln_k<<<Bb * NCH, blk, 0, stream>>>(valb, part, qb2, gamma, beta, h); // ln -> h[M,1024]

    // GEMM-C: ln @ Wo + bo + x -> out (f32)
    gemm128_k<2><<<128 * 8, blk, 0, stream>>>(h, 1024, woT, bo, x, nullptr, nullptr, out, 1024);
}